// Round 8
// baseline (133.092 us; speedup 1.0000x reference)
//
#include <hip/hip_runtime.h>
#include <stdint.h>

#define NN 4096
#define FF 256
#define HH 4
#define DD 64
#define NEG 0.2f
#define LOG2E 1.4426950408889634f

#define ITILE 32
#define CJ 64
#define NB (NN / 8)             // 512 j-blocks of 8

typedef __attribute__((ext_vector_type(8))) short short8;
typedef __attribute__((ext_vector_type(4))) float f32x4;
typedef __attribute__((ext_vector_type(16))) float f32x16;

__device__ __forceinline__ uint16_t bf16_rh(float f) {
    uint32_t u = __float_as_uint(f);
    return (uint16_t)((u + 0x8000u) >> 16);
}
// single-instr packed f32x2 -> bf16x2 (RNE); T12 recipe, no builtin on gfx950
__device__ __forceinline__ uint32_t cvtpk(float lo, float hi) {
    uint32_t r;
    asm("v_cvt_pk_bf16_f32 %0, %1, %2" : "=v"(r) : "v"(lo), "v"(hi));
    return r;
}

// ---------------- h = x @ W^T (bf16 MFMA) -----------------------------------
// x-tile and W-slice staged coalesced into LDS as bf16 (cvt via v_cvt_pk),
// fragments read from LDS. Epilogue: s,t dots (log2-scaled), B-fragment-
// packed Bf store, pden zeroing. grid (NN/64, HH).
__global__ __launch_bounds__(256) void gemm_h(const float* __restrict__ x,
                                              const float* __restrict__ W,
                                              const float* __restrict__ a_src,
                                              const float* __restrict__ a_dst,
                                              float* __restrict__ s,
                                              float* __restrict__ T_T,
                                              uint16_t* __restrict__ Bf,
                                              float* __restrict__ pden) {
    __shared__ uint16_t xs[64][264];              // 33 KB
    __shared__ uint16_t wsl[64][264];             // 33 KB
    const int tid = threadIdx.x;
    if (blockIdx.y == 0) pden[blockIdx.x * 256 + tid] = 0.f;  // 64 blk * 256 = NN*HH
    const int i0g = blockIdx.x * 64;
    const int f0 = blockIdx.y * 64;
    const int hh = blockIdx.y;                    // head index
    const float* xsrc = x + (size_t)i0g * FF;     // contiguous 64x256 tile
    const float* wsrc = W + (size_t)f0 * FF;      // contiguous 64x256 slice
    {
        const int rw = tid >> 6, c4 = (tid & 63) * 4;
#pragma unroll
        for (int p = 0; p < 16; p++) {
            float4 vx = ((const float4*)xsrc)[p * 256 + tid];
            float4 vw = ((const float4*)wsrc)[p * 256 + tid];
            *(uint2*)&xs[p * 4 + rw][c4] =
                make_uint2(cvtpk(vx.x, vx.y), cvtpk(vx.z, vx.w));
            *(uint2*)&wsl[p * 4 + rw][c4] =
                make_uint2(cvtpk(vw.x, vw.y), cvtpk(vw.z, vw.w));
        }
    }
    __syncthreads();
    const int w = tid >> 6, l = tid & 63;
    const int m = l & 15, q = l >> 4;             // 16x16x32: m=l&15, k=q*8+j
    const int i0 = i0g + w * 16;
    f32x4 acc[4];
#pragma unroll
    for (int n = 0; n < 4; n++)
#pragma unroll
        for (int r = 0; r < 4; r++) acc[n][r] = 0.f;
    const uint16_t* ax = &xs[w * 16 + m][q * 8];
#pragma unroll
    for (int k0 = 0; k0 < 8; k0++) {
        short8 af = *(const short8*)(ax + k0 * 32);
#pragma unroll
        for (int n = 0; n < 4; n++) {
            short8 bf = *(const short8*)&wsl[n * 16 + m][k0 * 32 + q * 8];
            acc[n] = __builtin_amdgcn_mfma_f32_16x16x32_bf16(af, bf, acc[n], 0, 0, 0);
        }
    }
    // ---- fused epilogue: s,t dots (log2-scaled) ----
    const float* as = a_src + hh * DD;
    const float* ad = a_dst + hh * DD;
    float av[4], dv[4];
#pragma unroll
    for (int n = 0; n < 4; n++) { av[n] = as[n * 16 + m]; dv[n] = ad[n * 16 + m]; }
#pragma unroll
    for (int r = 0; r < 4; r++) {
        float vs = 0.f, vd = 0.f;
#pragma unroll
        for (int n = 0; n < 4; n++) {
            vs = fmaf(acc[n][r], av[n], vs);
            vd = fmaf(acc[n][r], dv[n], vd);
        }
#pragma unroll
        for (int off = 1; off < 16; off <<= 1) {  // reduce across m
            vs += __shfl_xor(vs, off, 64);
            vd += __shfl_xor(vd, off, 64);
        }
        if (m == 0) {
            const int i = i0 + q * 4 + r;         // C: col=l&15 -> f, row=q*4+r -> i
            s[(size_t)i * HH + hh] = vs * LOG2E;  // log2-domain scores
            T_T[(size_t)hh * NN + i] = vd * LOG2E;
        }
    }
    // ---- fused epilogue: B-fragment-packed store ----
    // value acc[n][r] = h[i=i0+q*4+r][f=f0+n*16+m]; iblk=i/8, jj=i%8.
    const int iblk = blockIdx.x * 8 + w * 2 + (q >> 1);
    const int jjo  = (q & 1) * 4;                 // r=0..3 contiguous
#pragma unroll
    for (int n = 0; n < 4; n++) {
        *(uint2*)(Bf + (((size_t)hh * NB + iblk) * 64 + n * 16 + m) * 8 + jjo) =
            make_uint2(cvtpk(acc[n][0], acc[n][1]), cvtpk(acc[n][2], acc[n][3]));
    }
}

// ---------------- fused scores -> exp2 -> P -> MFMA PV ----------------------
// R7 post-mortem: conflicts=0, VALU cheap, still 42us -> latency-bound at
// ~2.5 waves/SIMD (grid 1024 = exactly 4 blocks/CU was the cap). This round:
// NSt=16 -> grid 2048 (8 blocks/CU of work), CJ=64 -> LDS 18KB so residency
// becomes reg-limited (~5/SIMD) not grid-limited; t staged in LDS with adj
// (kills the 2 per-step global t loads, ~200cy L2, from the chain).
// LDS swizzle at 8-j granularity: (j,i) at [j][i ^ ((j>>3 & 7)<<2)] --
// writes 2-way (free), reads a permutation. P-pack via v_cvt_pk_bf16_f32.
template<int NSt>
__global__ __launch_bounds__(256, 4) void gat_main(
    const float* __restrict__ adj, const uint16_t* __restrict__ Bf,
    const float* __restrict__ s, const float* __restrict__ T_T,
    float* __restrict__ pden, uint16_t* __restrict__ part) {
    constexpr int JRt = NN / NSt;
    constexpr int NCH = JRt / CJ;
    __shared__ float adj_s[2][CJ][32];            // 16 KB
    __shared__ float ts[2][HH][CJ];               // 2 KB
    const int tid = threadIdx.x;
    const int w = tid >> 6, l = tid & 63;
    const int m = l & 31, q = l >> 5;             // 32x32x16: m=l&31, k=q*8+j
    // bijective XCD swizzle (nwg % 8 == 0): same-XCD blocks share a j-slice
    constexpr int NWG = (NN / ITILE) * NSt;
    const int orig = blockIdx.y * (NN / ITILE) + blockIdx.x;
    const int swz = (orig & 7) * (NWG / 8) + (orig >> 3);
    const int i0 = (swz & (NN / ITILE - 1)) * ITILE;
    const int sl = swz / (NN / ITILE);
    const int jb = sl * JRt;

    const float sS = s[(size_t)(i0 + m) * HH + w];  // *log2e already
    const float sB = NEG * sS;
    float den = 0.f;
    f32x16 acc0, acc1;
#pragma unroll
    for (int r = 0; r < 16; r++) { acc0[r] = 0.f; acc1[r] = 0.f; }
    const uint16_t* bbase = Bf + (size_t)w * NB * 512;  // 512 u16 per jblk
    const float* tsrc = T_T + (size_t)w * NN + l;       // wave w stages head w's t

    // adj staging: thread stages adj[i0+is][jc+j8 .. +7] (2 float4)
    const int is = tid >> 3, r7 = tid & 7, j8 = r7 * 8;
    const int colw = is ^ (r7 << 2);              // swizzle key = j>>3 = r7
    const float* arow = adj + (size_t)(i0 + is) * NN + j8;

    float4 p0 = *(const float4*)(arow + jb);
    float4 p1 = *(const float4*)(arow + jb + 4);
    float tp = tsrc[jb];
    adj_s[0][j8 + 0][colw] = p0.x; adj_s[0][j8 + 1][colw] = p0.y;
    adj_s[0][j8 + 2][colw] = p0.z; adj_s[0][j8 + 3][colw] = p0.w;
    adj_s[0][j8 + 4][colw] = p1.x; adj_s[0][j8 + 5][colw] = p1.y;
    adj_s[0][j8 + 6][colw] = p1.z; adj_s[0][j8 + 7][colw] = p1.w;
    ts[0][w][l] = tp;
    p0 = *(const float4*)(arow + jb + CJ);
    p1 = *(const float4*)(arow + jb + CJ + 4);
    tp = tsrc[jb + CJ];
    __syncthreads();

    for (int c = 0; c < NCH; ++c) {
        const int jc = jb + c * CJ;
        const int cur = c & 1;
        if (c + 1 < NCH) {                        // write chunk c+1 into other buf
            const int nb = cur ^ 1;
            adj_s[nb][j8 + 0][colw] = p0.x; adj_s[nb][j8 + 1][colw] = p0.y;
            adj_s[nb][j8 + 2][colw] = p0.z; adj_s[nb][j8 + 3][colw] = p0.w;
            adj_s[nb][j8 + 4][colw] = p1.x; adj_s[nb][j8 + 5][colw] = p1.y;
            adj_s[nb][j8 + 6][colw] = p1.z; adj_s[nb][j8 + 7][colw] = p1.w;
            ts[nb][w][l] = tp;
            if (c + 2 < NCH) {                    // prefetch chunk c+2 -> regs
                p0 = *(const float4*)(arow + jc + 2 * CJ);
                p1 = *(const float4*)(arow + jc + 2 * CJ + 4);
                tp = tsrc[jc + 2 * CJ];
            }
        }
#pragma unroll
        for (int kk = 0; kk < CJ; kk += 16) {
            const int jblk = ((jc + kk) >> 3) + q;
            const int cmv = m ^ ((((kk >> 3) + q) & 7) << 2);  // read col (swizzled)
            const float* tptr = &ts[cur][w][kk + q * 8];       // LDS broadcast
            float4 t0 = *(const float4*)tptr;
            float4 t1 = *(const float4*)(tptr + 4);
            short8 bf0 = *(const short8*)(bbase + (size_t)jblk * 512 + m * 8);
            short8 bf1 = *(const short8*)(bbase + (size_t)jblk * 512 + (32 + m) * 8);
            float tt[8] = {t0.x, t0.y, t0.z, t0.w, t1.x, t1.y, t1.z, t1.w};
            union { uint32_t u[4]; short8 v; } afu;
#pragma unroll
            for (int jj = 0; jj < 8; jj += 2) {
                const int rr = kk + q * 8 + jj;
                float a0 = adj_s[cur][rr][cmv], a1 = adj_s[cur][rr + 1][cmv];
                float tv0 = tt[jj], tv1 = tt[jj + 1];
                // lrelu in log2 domain: max(S+T, 0.2*(S+T)); exp2 direct
                float x0 = sS + tv0,           x1 = sS + tv1;
                float z0 = fmaf(NEG, tv0, sB), z1 = fmaf(NEG, tv1, sB);
                float lr0 = fmaxf(x0, z0), lr1 = fmaxf(x1, z1);
                float e0, e1;
                asm("v_exp_f32 %0, %1" : "=v"(e0) : "v"(lr0));
                asm("v_exp_f32 %0, %1" : "=v"(e1) : "v"(lr1));
                e0 = (a0 > 0.f) ? e0 : 0.f;
                e1 = (a1 > 0.f) ? e1 : 0.f;
                den += e0 + e1;
                afu.u[jj >> 1] = cvtpk(e0 * a0, e1 * a1);
            }
            acc0 = __builtin_amdgcn_mfma_f32_32x32x16_bf16(afu.v, bf0, acc0, 0, 0, 0);
            acc1 = __builtin_amdgcn_mfma_f32_32x32x16_bf16(afu.v, bf1, acc1, 0, 0, 0);
        }
        __syncthreads();
    }
    den += __shfl_down(den, 32, 64);              // lanes l and l+32 share m
    if (l < 32) atomicAdd(&pden[(size_t)(i0 + m) * HH + w], den);
    uint16_t* pbase = part + (size_t)sl * NN * FF;
#pragma unroll
    for (int reg = 0; reg < 16; reg++) {
        int row = (reg & 3) + 8 * (reg >> 2) + 4 * q;  // C: col=l&31, verified m74
        pbase[(size_t)(i0 + row) * FF + w * DD + m]      = bf16_rh(acc0[reg]);
        pbase[(size_t)(i0 + row) * FF + w * DD + 32 + m] = bf16_rh(acc1[reg]);
    }
}

// ---------------- sum slice partials, divide by denom (vectorized) ----------
// block: 8 i-rows x 32 lanes; thread handles 8 consecutive f via short8 (16B).
template<int NSt>
__global__ __launch_bounds__(256) void finalize(const uint16_t* __restrict__ part,
                                                const float* __restrict__ pden,
                                                float* __restrict__ out) {
    const int i = blockIdx.x * 8 + (threadIdx.x >> 5);
    const int f8 = (threadIdx.x & 31) * 8;
    float acc[8];
#pragma unroll
    for (int e = 0; e < 8; e++) acc[e] = 0.f;
#pragma unroll
    for (int sl = 0; sl < NSt; sl++) {
        union { short8 v; uint16_t u[8]; } b;
        b.v = *(const short8*)(part + (size_t)sl * NN * FF + (size_t)i * FF + f8);
#pragma unroll
        for (int e = 0; e < 8; e++)
            acc[e] += __uint_as_float(((uint32_t)b.u[e]) << 16);
    }
    float d = pden[(size_t)i * HH + (f8 >> 6)];
    float inv = (d > 0.f) ? 1.f / d : 0.f;
    *(float4*)(out + (size_t)i * FF + f8) =
        make_float4(acc[0] * inv, acc[1] * inv, acc[2] * inv, acc[3] * inv);
    *(float4*)(out + (size_t)i * FF + f8 + 4) =
        make_float4(acc[4] * inv, acc[5] * inv, acc[6] * inv, acc[7] * inv);
}

extern "C" void kernel_launch(void* const* d_in, const int* in_sizes, int n_in,
                              void* d_out, int out_size, void* d_ws, size_t ws_size,
                              hipStream_t stream) {
    const float* x     = (const float*)d_in[0];
    const float* adj   = (const float*)d_in[1];
    const float* W     = (const float*)d_in[2];
    const float* a_src = (const float*)d_in[3];
    const float* a_dst = (const float*)d_in[4];
    float* out = (float*)d_out;

    char* ws = (char*)d_ws;
    uint16_t* Bf   = (uint16_t*)ws;                                // 2 MB
    float*    s    = (float*)(ws + (2u << 20));                    // 64 KB
    float*    T_T  = s + (size_t)NN * HH;                          // 64 KB
    float*    pden = T_T + (size_t)HH * NN;                        // 64 KB
    uint16_t* part = (uint16_t*)(ws + (3u << 20));                 // NSt * 2 MB

    gemm_h<<<dim3(NN / 64, HH), 256, 0, stream>>>(x, W, a_src, a_dst, s, T_T, Bf, pden);
    if (ws_size >= (3u << 20) + (size_t)16 * NN * FF * sizeof(uint16_t)) {
        gat_main<16><<<dim3(NN / ITILE, 16), 256, 0, stream>>>(adj, Bf, s, T_T, pden, part);
        finalize<16><<<NN / 8, 256, 0, stream>>>(part, pden, out);
    } else {
        gat_main<8><<<dim3(NN / ITILE, 8), 256, 0, stream>>>(adj, Bf, s, T_T, pden, part);
        finalize<8><<<NN / 8, 256, 0, stream>>>(part, pden, out);
    }
}

// Round 9
// 130.892 us; speedup vs baseline: 1.0168x; 1.0168x over previous
//
#include <hip/hip_runtime.h>
#include <stdint.h>

#define NN 4096
#define FF 256
#define HH 4
#define DD 64
#define NEG 0.2f
#define LOG2E 1.4426950408889634f

#define ITILE 32
#define NS 8
#define JR (NN / NS)            // 512
#define CJ 64
#define NCH (JR / CJ)           // 8
#define NB (NN / 8)             // 512 j-blocks of 8

typedef __attribute__((ext_vector_type(8))) short short8;
typedef __attribute__((ext_vector_type(4))) float f32x4;
typedef __attribute__((ext_vector_type(16))) float f32x16;

__device__ __forceinline__ uint16_t bf16_rh(float f) {
    uint32_t u = __float_as_uint(f);
    return (uint16_t)((u + 0x8000u) >> 16);
}
// single-instr packed f32x2 -> bf16x2 (RNE); T12 recipe, no builtin on gfx950
__device__ __forceinline__ uint32_t cvtpk(float lo, float hi) {
    uint32_t r;
    asm("v_cvt_pk_bf16_f32 %0, %1, %2" : "=v"(r) : "v"(lo), "v"(hi));
    return r;
}

// ---------------- h = x @ W^T (bf16 MFMA) -----------------------------------
// R8 post-mortem: old grid (64,4) = 1 block/CU -> a block's ~66KB stage
// latency had NOTHING to overlap it. Now grid (128,4), 128-thread blocks
// (32 i x 64 f): 2 blocks/CU, half the stage per block; block B's compute
// covers block A's staging. Epilogue unchanged: s,t dots (log2-scaled),
// B-fragment-packed Bf store, pden zeroing.
__global__ __launch_bounds__(128) void gemm_h(const float* __restrict__ x,
                                              const float* __restrict__ W,
                                              const float* __restrict__ a_src,
                                              const float* __restrict__ a_dst,
                                              float* __restrict__ s,
                                              float* __restrict__ T_T,
                                              uint16_t* __restrict__ Bf,
                                              float* __restrict__ pden) {
    __shared__ uint16_t xs[32][264];              // 16.9 KB
    __shared__ uint16_t wsl[64][264];             // 33.8 KB
    const int tid = threadIdx.x;
    if (blockIdx.y == 0) pden[blockIdx.x * 128 + tid] = 0.f;  // 128 blk * 128 = NN*HH
    const int i0g = blockIdx.x * 32;
    const int f0 = blockIdx.y * 64;
    const int hh = blockIdx.y;                    // head index
    const float* xsrc = x + (size_t)i0g * FF;     // contiguous 32x256 tile
    const float* wsrc = W + (size_t)f0 * FF;      // contiguous 64x256 slice
#pragma unroll
    for (int p = 0; p < 16; p++) {                // 2048 float4 / 128 thr
        const int gi = p * 128 + tid;
        float4 vx = ((const float4*)xsrc)[gi];
        *(uint2*)&xs[gi >> 6][(gi & 63) * 4] =
            make_uint2(cvtpk(vx.x, vx.y), cvtpk(vx.z, vx.w));
    }
#pragma unroll
    for (int p = 0; p < 32; p++) {                // 4096 float4 / 128 thr
        const int gi = p * 128 + tid;
        float4 vw = ((const float4*)wsrc)[gi];
        *(uint2*)&wsl[gi >> 6][(gi & 63) * 4] =
            make_uint2(cvtpk(vw.x, vw.y), cvtpk(vw.z, vw.w));
    }
    __syncthreads();
    const int w = tid >> 6, l = tid & 63;         // 2 waves: i-halves
    const int m = l & 15, q = l >> 4;             // 16x16x32: m=l&15, k=q*8+j
    const int i0 = i0g + w * 16;
    f32x4 acc[4];
#pragma unroll
    for (int n = 0; n < 4; n++)
#pragma unroll
        for (int r = 0; r < 4; r++) acc[n][r] = 0.f;
    const uint16_t* ax = &xs[w * 16 + m][q * 8];
#pragma unroll
    for (int k0 = 0; k0 < 8; k0++) {
        short8 af = *(const short8*)(ax + k0 * 32);
#pragma unroll
        for (int n = 0; n < 4; n++) {
            short8 bf = *(const short8*)&wsl[n * 16 + m][k0 * 32 + q * 8];
            acc[n] = __builtin_amdgcn_mfma_f32_16x16x32_bf16(af, bf, acc[n], 0, 0, 0);
        }
    }
    // ---- fused epilogue: s,t dots (log2-scaled) ----
    const float* as = a_src + hh * DD;
    const float* ad = a_dst + hh * DD;
    float av[4], dv[4];
#pragma unroll
    for (int n = 0; n < 4; n++) { av[n] = as[n * 16 + m]; dv[n] = ad[n * 16 + m]; }
#pragma unroll
    for (int r = 0; r < 4; r++) {
        float vs = 0.f, vd = 0.f;
#pragma unroll
        for (int n = 0; n < 4; n++) {
            vs = fmaf(acc[n][r], av[n], vs);
            vd = fmaf(acc[n][r], dv[n], vd);
        }
#pragma unroll
        for (int off = 1; off < 16; off <<= 1) {  // reduce across m
            vs += __shfl_xor(vs, off, 64);
            vd += __shfl_xor(vd, off, 64);
        }
        if (m == 0) {
            const int i = i0 + q * 4 + r;         // C: col=l&15 -> f, row=q*4+r -> i
            s[(size_t)i * HH + hh] = vs * LOG2E;  // log2-domain scores
            T_T[(size_t)hh * NN + i] = vd * LOG2E;
        }
    }
    // ---- fused epilogue: B-fragment-packed store ----
    // value acc[n][r] = h[i=i0+q*4+r][f=f0+n*16+m]; iblk=i/8, jj=i%8.
    const int iblk = blockIdx.x * 4 + w * 2 + (q >> 1);
    const int jjo  = (q & 1) * 4;                 // r=0..3 contiguous
#pragma unroll
    for (int n = 0; n < 4; n++) {
        *(uint2*)(Bf + (((size_t)hh * NB + iblk) * 64 + n * 16 + m) * 8 + jjo) =
            make_uint2(cvtpk(acc[n][0], acc[n][1]), cvtpk(acc[n][2], acc[n][3]));
    }
}

// ---------------- fused scores -> exp2 -> P -> MFMA PV ----------------------
// R8 post-mortem: kk-step issued 8 scalar ds_read_b32 (lane reads 8 rows of
// adj_s[j][i]). Now LDS holds the TRANSPOSED tile adj_t[i][j] with row
// stride 68 dwords (272B, 16B-aligned): lane (m,q) reads its 8 j's as
// 2 x ds_read_b128. Odd stride makes both read (4(m&7)+8q) and write
// (4(is&7)+8(r7&3)) patterns hit 8 lanes per 4-bank group = the 64-lane
// minimum -- conflict-free, no XOR needed. t staged in LDS (broadcast
// reads). Double-buffered, one barrier per 64-j chunk, reg prefetch.
__global__ __launch_bounds__(256, 4) void gat_main(
    const float* __restrict__ adj, const uint16_t* __restrict__ Bf,
    const float* __restrict__ s, const float* __restrict__ T_T,
    float* __restrict__ pden, uint16_t* __restrict__ part) {
    __shared__ float adj_t[2][32][68];            // 17.4 KB, transposed [i][j]
    __shared__ float ts[2][HH][CJ];               // 2 KB
    const int tid = threadIdx.x;
    const int w = tid >> 6, l = tid & 63;
    const int m = l & 31, q = l >> 5;             // 32x32x16: m=l&31, k=q*8+j
    // bijective XCD swizzle (nwg % 8 == 0): same-XCD blocks share a j-slice
    constexpr int NWG = (NN / ITILE) * NS;
    const int orig = blockIdx.y * (NN / ITILE) + blockIdx.x;
    const int swz = (orig & 7) * (NWG / 8) + (orig >> 3);
    const int i0 = (swz & (NN / ITILE - 1)) * ITILE;
    const int sl = swz / (NN / ITILE);
    const int jb = sl * JR;

    const float sS = s[(size_t)(i0 + m) * HH + w];  // *log2e already
    const float sB = NEG * sS;
    float den = 0.f;
    f32x16 acc0, acc1;
#pragma unroll
    for (int r = 0; r < 16; r++) { acc0[r] = 0.f; acc1[r] = 0.f; }
    const uint16_t* bbase = Bf + (size_t)w * NB * 512;  // 512 u16 per jblk
    const float* tsrc = T_T + (size_t)w * NN + l;       // wave w stages head w's t

    // adj staging: thread stages adj[i0+is][jc+j8 .. +7] (2 float4)
    const int is = tid >> 3, r7 = tid & 7, j8 = r7 * 8;
    const float* arow = adj + (size_t)(i0 + is) * NN + j8;

    float4 p0 = *(const float4*)(arow + jb);
    float4 p1 = *(const float4*)(arow + jb + 4);
    float tp = tsrc[jb];
    *(float4*)&adj_t[0][is][j8]     = p0;
    *(float4*)&adj_t[0][is][j8 + 4] = p1;
    ts[0][w][l] = tp;
    p0 = *(const float4*)(arow + jb + CJ);
    p1 = *(const float4*)(arow + jb + CJ + 4);
    tp = tsrc[jb + CJ];
    __syncthreads();

    for (int c = 0; c < NCH; ++c) {
        const int jc = jb + c * CJ;
        const int cur = c & 1;
        if (c + 1 < NCH) {                        // write chunk c+1 into other buf
            const int nb = cur ^ 1;
            *(float4*)&adj_t[nb][is][j8]     = p0;
            *(float4*)&adj_t[nb][is][j8 + 4] = p1;
            ts[nb][w][l] = tp;
            if (c + 2 < NCH) {                    // prefetch chunk c+2 -> regs
                p0 = *(const float4*)(arow + jc + 2 * CJ);
                p1 = *(const float4*)(arow + jc + 2 * CJ + 4);
                tp = tsrc[jc + 2 * CJ];
            }
        }
#pragma unroll
        for (int kk = 0; kk < CJ; kk += 16) {
            const int jblk = ((jc + kk) >> 3) + q;
            const float* ap = &adj_t[cur][m][kk + q * 8];      // 2 x b128
            float4 a0v = *(const float4*)ap;
            float4 a1v = *(const float4*)(ap + 4);
            const float* tptr = &ts[cur][w][kk + q * 8];       // LDS broadcast
            float4 t0 = *(const float4*)tptr;
            float4 t1 = *(const float4*)(tptr + 4);
            short8 bf0 = *(const short8*)(bbase + (size_t)jblk * 512 + m * 8);
            short8 bf1 = *(const short8*)(bbase + (size_t)jblk * 512 + (32 + m) * 8);
            float aa[8] = {a0v.x, a0v.y, a0v.z, a0v.w, a1v.x, a1v.y, a1v.z, a1v.w};
            float tt[8] = {t0.x, t0.y, t0.z, t0.w, t1.x, t1.y, t1.z, t1.w};
            union { uint32_t u[4]; short8 v; } afu;
#pragma unroll
            for (int jj = 0; jj < 8; jj += 2) {
                float a0 = aa[jj], a1 = aa[jj + 1];
                float tv0 = tt[jj], tv1 = tt[jj + 1];
                // lrelu in log2 domain: max(S+T, 0.2*(S+T)); exp2 direct
                float x0 = sS + tv0,           x1 = sS + tv1;
                float z0 = fmaf(NEG, tv0, sB), z1 = fmaf(NEG, tv1, sB);
                float lr0 = fmaxf(x0, z0), lr1 = fmaxf(x1, z1);
                float e0, e1;
                asm("v_exp_f32 %0, %1" : "=v"(e0) : "v"(lr0));
                asm("v_exp_f32 %0, %1" : "=v"(e1) : "v"(lr1));
                e0 = (a0 > 0.f) ? e0 : 0.f;
                e1 = (a1 > 0.f) ? e1 : 0.f;
                den += e0 + e1;
                afu.u[jj >> 1] = cvtpk(e0 * a0, e1 * a1);
            }
            acc0 = __builtin_amdgcn_mfma_f32_32x32x16_bf16(afu.v, bf0, acc0, 0, 0, 0);
            acc1 = __builtin_amdgcn_mfma_f32_32x32x16_bf16(afu.v, bf1, acc1, 0, 0, 0);
        }
        __syncthreads();
    }
    den += __shfl_down(den, 32, 64);              // lanes l and l+32 share m
    if (l < 32) atomicAdd(&pden[(size_t)(i0 + m) * HH + w], den);
    uint16_t* pbase = part + (size_t)sl * NN * FF;
#pragma unroll
    for (int reg = 0; reg < 16; reg++) {
        int row = (reg & 3) + 8 * (reg >> 2) + 4 * q;  // C: col=l&31, verified m74
        pbase[(size_t)(i0 + row) * FF + w * DD + m]      = bf16_rh(acc0[reg]);
        pbase[(size_t)(i0 + row) * FF + w * DD + 32 + m] = bf16_rh(acc1[reg]);
    }
}

// ---------------- sum slice partials, divide by denom (vectorized) ----------
// block: 8 i-rows x 32 lanes; thread handles 8 consecutive f via short8 (16B).
__global__ __launch_bounds__(256) void finalize(const uint16_t* __restrict__ part,
                                                const float* __restrict__ pden,
                                                float* __restrict__ out) {
    const int i = blockIdx.x * 8 + (threadIdx.x >> 5);
    const int f8 = (threadIdx.x & 31) * 8;
    float acc[8];
#pragma unroll
    for (int e = 0; e < 8; e++) acc[e] = 0.f;
#pragma unroll
    for (int sl = 0; sl < NS; sl++) {
        union { short8 v; uint16_t u[8]; } b;
        b.v = *(const short8*)(part + (size_t)sl * NN * FF + (size_t)i * FF + f8);
#pragma unroll
        for (int e = 0; e < 8; e++)
            acc[e] += __uint_as_float(((uint32_t)b.u[e]) << 16);
    }
    float d = pden[(size_t)i * HH + (f8 >> 6)];
    float inv = (d > 0.f) ? 1.f / d : 0.f;
    *(float4*)(out + (size_t)i * FF + f8) =
        make_float4(acc[0] * inv, acc[1] * inv, acc[2] * inv, acc[3] * inv);
    *(float4*)(out + (size_t)i * FF + f8 + 4) =
        make_float4(acc[4] * inv, acc[5] * inv, acc[6] * inv, acc[7] * inv);
}

extern "C" void kernel_launch(void* const* d_in, const int* in_sizes, int n_in,
                              void* d_out, int out_size, void* d_ws, size_t ws_size,
                              hipStream_t stream) {
    const float* x     = (const float*)d_in[0];
    const float* adj   = (const float*)d_in[1];
    const float* W     = (const float*)d_in[2];
    const float* a_src = (const float*)d_in[3];
    const float* a_dst = (const float*)d_in[4];
    float* out = (float*)d_out;

    char* ws = (char*)d_ws;
    uint16_t* Bf   = (uint16_t*)ws;                                // 2 MB
    float*    s    = (float*)(ws + (2u << 20));                    // 64 KB
    float*    T_T  = s + (size_t)NN * HH;                          // 64 KB
    float*    pden = T_T + (size_t)HH * NN;                        // 64 KB
    uint16_t* part = (uint16_t*)(ws + (3u << 20));                 // NS * 2 MB = 16 MB

    gemm_h<<<dim3(NN / 32, HH), 128, 0, stream>>>(x, W, a_src, a_dst, s, T_T, Bf, pden);
    gat_main<<<dim3(NN / ITILE, NS), 256, 0, stream>>>(adj, Bf, s, T_T, pden, part);
    finalize<<<NN / 8, 256, 0, stream>>>(part, pden, out);
}